// Round 9
// baseline (309.241 us; speedup 1.0000x reference)
//
#include <hip/hip_runtime.h>

typedef short bf16x8 __attribute__((ext_vector_type(8)));
typedef float f32x4  __attribute__((ext_vector_type(4)));
typedef int   i32x4  __attribute__((ext_vector_type(4)));
typedef unsigned int u32x4 __attribute__((ext_vector_type(4)));

__device__ __forceinline__ unsigned short f32_to_bf16(float f) {
  union { float f; unsigned int u; } v; v.f = f;
  unsigned int u = v.u;
  u += 0x7fffu + ((u >> 16) & 1u);   // round-to-nearest-even
  return (unsigned short)(u >> 16);
}
__device__ __forceinline__ float bf16lo_to_f32(unsigned int u) {
  union { unsigned int u; float f; } v; v.u = u << 16; return v.f;
}
__device__ __forceinline__ float bf16hi_to_f32(unsigned int u) {
  union { unsigned int u; float f; } v; v.u = u & 0xffff0000u; return v.f;
}

// h = x @ W.T + b, h[0,:] = 0, stored as bf16.
// r0-proven structure: 256 threads = 4 waves; wave w covers cols [w*64,w*64+64).
// sliced=1 writes h_s[s][row][32] (s = col>>5) for the XCD-sliced gather.
__global__ __launch_bounds__(256, 2) void gin_gemm(
    const float* __restrict__ x, const float* __restrict__ W,
    const float* __restrict__ bias, unsigned short* __restrict__ h, int M,
    int sliced) {
  __shared__ __align__(16) unsigned short As[64 * 32];   // [row][k]  4 KB
  __shared__ __align__(16) unsigned short Bs[256 * 32];  // [col][k] 16 KB

  const int tid  = threadIdx.x;
  const int wid  = tid >> 6;
  const int lane = tid & 63;
  const int row0 = blockIdx.x * 64;

  f32x4 acc[4][4] = {};  // [row-group][col-group], 64 VGPRs

  const int srow = tid >> 2;          // 0..63
  const int sk0  = (tid & 3) << 3;    // 0,8,16,24
  int agrow = row0 + srow;
  if (agrow >= M) agrow = M - 1;      // clamp; results discarded in epilogue
  const float* aRow = x + (size_t)agrow * 256 + sk0;
  const float* bRow = W + (size_t)srow * 256 + sk0;

  for (int kt = 0; kt < 8; ++kt) {
    const int kb = kt * 32;
    // stage A: 64x32 f32 -> bf16
    {
      float4 v0 = *(const float4*)(aRow + kb);
      float4 v1 = *(const float4*)(aRow + kb + 4);
      bf16x8 u;
      u[0] = (short)f32_to_bf16(v0.x); u[1] = (short)f32_to_bf16(v0.y);
      u[2] = (short)f32_to_bf16(v0.z); u[3] = (short)f32_to_bf16(v0.w);
      u[4] = (short)f32_to_bf16(v1.x); u[5] = (short)f32_to_bf16(v1.y);
      u[6] = (short)f32_to_bf16(v1.z); u[7] = (short)f32_to_bf16(v1.w);
      *(bf16x8*)(&As[srow * 32 + sk0]) = u;
    }
    // stage B: 256x32 (W rows = output cols)
#pragma unroll
    for (int j = 0; j < 4; ++j) {
      const float* p = bRow + (size_t)(j * 64) * 256 + kb;
      float4 v0 = *(const float4*)p;
      float4 v1 = *(const float4*)(p + 4);
      bf16x8 u;
      u[0] = (short)f32_to_bf16(v0.x); u[1] = (short)f32_to_bf16(v0.y);
      u[2] = (short)f32_to_bf16(v0.z); u[3] = (short)f32_to_bf16(v0.w);
      u[4] = (short)f32_to_bf16(v1.x); u[5] = (short)f32_to_bf16(v1.y);
      u[6] = (short)f32_to_bf16(v1.z); u[7] = (short)f32_to_bf16(v1.w);
      *(bf16x8*)(&Bs[(j * 64 + srow) * 32 + sk0]) = u;
    }
    __syncthreads();

    const int r16 = lane & 15;
    const int qk  = (lane >> 4) << 3;  // k-offset 0/8/16/24
    bf16x8 af[4], bfr[4];
#pragma unroll
    for (int g = 0; g < 4; ++g)
      af[g] = *(const bf16x8*)(&As[(g * 16 + r16) * 32 + qk]);
#pragma unroll
    for (int g = 0; g < 4; ++g)
      bfr[g] = *(const bf16x8*)(&Bs[(wid * 64 + g * 16 + r16) * 32 + qk]);
#pragma unroll
    for (int rg = 0; rg < 4; ++rg)
#pragma unroll
      for (int cg = 0; cg < 4; ++cg)
        acc[rg][cg] = __builtin_amdgcn_mfma_f32_16x16x32_bf16(
            af[rg], bfr[cg], acc[rg][cg], 0, 0, 0);
    __syncthreads();
  }

  // epilogue: C/D layout col=lane&15, row=(lane>>4)*4+reg
  const int quad = lane >> 4;
  const int c16  = lane & 15;
#pragma unroll
  for (int rg = 0; rg < 4; ++rg) {
#pragma unroll
    for (int r = 0; r < 4; ++r) {
      int grow = row0 + rg * 16 + quad * 4 + r;
      if (grow >= M) continue;
#pragma unroll
      for (int cg = 0; cg < 4; ++cg) {
        int col = wid * 64 + cg * 16 + c16;
        float v = acc[rg][cg][r] + bias[col];
        if (grow == 0) v = 0.0f;  // padding row
        unsigned short hv = f32_to_bf16(v);
        if (sliced) {
          h[((size_t)(col >> 5) * M + grow) * 32 + (col & 31)] = hv;
        } else {
          h[(size_t)grow * 256 + col] = hv;
        }
      }
    }
  }
}

// a2a[j] = b_from_a[a_from_b[j]], flattened so the gather has one coalesced
// index stream and no dependent chase.
__global__ __launch_bounds__(256, 8) void gin_a2a(
    const int* __restrict__ b_from_a, const int* __restrict__ a_from_b,
    int* __restrict__ a2a, int n) {
  int j = (blockIdx.x * 256 + threadIdx.x) * 4;
  if (j + 3 >= n) {
    for (; j < n; ++j) a2a[j] = b_from_a[a_from_b[j]];
    return;
  }
  i32x4 f = *(const i32x4*)(a_from_b + j);
  i32x4 r;
  r[0] = b_from_a[f[0]]; r[1] = b_from_a[f[1]];
  r[2] = b_from_a[f[2]]; r[3] = b_from_a[f[3]];
  *(i32x4*)(a2a + j) = r;
}

// XCD-sliced gather v3. slice = blockIdx.x & 7: deterministic coverage (every
// (slice, group) pair processed exactly once regardless of dispatch), with
// affinity as a PERFORMANCE hint (consecutive blocks round-robin across the 8
// XCDs, so each XCD's 4MB L2 serves its own 3.2MB h-slice, ~16 refs/row ->
// ~94% hit). v4 failure fixed: PLAIN cached stores (TCC merges the 128B
// per-atom segments into full lines; nt 16B stores caused 6.3x write
// amplification and flushed L2+L3). No atomics (v5 failure).
// Wave layout: 16 atoms/group, 4 lanes per atom, 16B (8 cols) per lane.
__global__ __launch_bounds__(256, 8) void gin_gather_sliced(
    const unsigned short* __restrict__ hs, const int* __restrict__ a2a,
    float* __restrict__ out, int M) {
  const int tid   = threadIdx.x;
  const int wid   = tid >> 6;
  const int lane  = tid & 63;
  const int slice = blockIdx.x & 7;
  const int chunk = blockIdx.x >> 3;       // 0..255
  const int a     = lane >> 2;             // atom-in-group 0..15
  const int sub   = lane & 3;              // 16B sub-chunk of the 64B slice row
  const unsigned short* __restrict__ hsl = hs + (size_t)slice * M * 32;
  const int ngroups = (M + 15) >> 4;       // 3125 for M=50000

  for (int g = chunk * 4 + wid; g < ngroups; g += 1024) {
    const int i0 = g * 16;
    // 256 neighbor ids for this 16-atom group; lane holds 4 (nt: index stream
    // must not evict the h-slice from L2)
    int idx = i0 * 16 + lane * 4;
    int lim = M * 16 - 4;
    if (idx > lim) idx = lim;
    i32x4 ids = __builtin_nontemporal_load((const i32x4*)(a2a + idx));

    float s0 = 0, s1 = 0, s2 = 0, s3 = 0, s4 = 0, s5 = 0, s6 = 0, s7 = 0;
#pragma unroll
    for (int k = 0; k < 16; ++k) {
      // flat = a*16+k -> source lane a*4 + (k>>2), element k&3 (compile-time)
      int id = __shfl(ids[k & 3], a * 4 + (k >> 2), 64);
      u32x4 v = *(const u32x4*)(hsl + (size_t)id * 32 + sub * 8);
      s0 += bf16lo_to_f32(v[0]); s1 += bf16hi_to_f32(v[0]);
      s2 += bf16lo_to_f32(v[1]); s3 += bf16hi_to_f32(v[1]);
      s4 += bf16lo_to_f32(v[2]); s5 += bf16hi_to_f32(v[2]);
      s6 += bf16lo_to_f32(v[3]); s7 += bf16hi_to_f32(v[3]);
    }
    // self term (h already contains bias; row 0 zeroed in GEMM)
    const int self  = i0 + a;
    const int selfc = self < M ? self : M - 1;
    u32x4 v = *(const u32x4*)(hsl + (size_t)selfc * 32 + sub * 8);
    s0 += bf16lo_to_f32(v[0]); s1 += bf16hi_to_f32(v[0]);
    s2 += bf16lo_to_f32(v[1]); s3 += bf16hi_to_f32(v[1]);
    s4 += bf16lo_to_f32(v[2]); s5 += bf16hi_to_f32(v[2]);
    s6 += bf16lo_to_f32(v[3]); s7 += bf16hi_to_f32(v[3]);

    if (self < M) {
      f32x4 r0, r1;
      r0[0] = fmaxf(s0, 0.0f); r0[1] = fmaxf(s1, 0.0f);
      r0[2] = fmaxf(s2, 0.0f); r0[3] = fmaxf(s3, 0.0f);
      r1[0] = fmaxf(s4, 0.0f); r1[1] = fmaxf(s5, 0.0f);
      r1[2] = fmaxf(s6, 0.0f); r1[3] = fmaxf(s7, 0.0f);
      float* op = out + (size_t)self * 256 + slice * 32 + sub * 8;
      *(f32x4*)op = r0;          // plain cached stores: merge in TCC
      *(f32x4*)(op + 4) = r1;
    }
  }
}

// Fallback gather (row-major h), used if workspace can't hold h + a2a.
__global__ __launch_bounds__(256, 4) void gin_gather(
    const unsigned short* __restrict__ h, const int* __restrict__ b_from_a,
    const int* __restrict__ a_from_b, float* __restrict__ out, int N) {
  const int tid  = threadIdx.x;
  const int wid  = tid >> 6;
  const int lane = tid & 63;
  const int half = lane >> 5;
  const int l32  = lane & 31;
  const int i0   = blockIdx.x * 8 + wid * 2;
  if (i0 >= N) return;
  const int row  = i0 + half;
  const int rowc = (row < N) ? row : (N - 1);

  int src = 0;
  if (lane < 32) {
    int idx = i0 * 16 + lane;
    int lim = N * 16 - 1;
    if (idx > lim) idx = lim;
    src = b_from_a[a_from_b[idx]];
  }

  const int c0 = l32 * 8;
  uint4 u = *(const uint4*)(h + (size_t)rowc * 256 + c0);
  float a0 = bf16lo_to_f32(u.x), a1 = bf16hi_to_f32(u.x);
  float a2 = bf16lo_to_f32(u.y), a3 = bf16hi_to_f32(u.y);
  float a4 = bf16lo_to_f32(u.z), a5 = bf16hi_to_f32(u.z);
  float a6 = bf16lo_to_f32(u.w), a7 = bf16hi_to_f32(u.w);

#pragma unroll
  for (int k = 0; k < 16; ++k) {
    int s = __shfl(src, half * 16 + k, 64);
    uint4 v = *(const uint4*)(h + (size_t)s * 256 + c0);
    a0 += bf16lo_to_f32(v.x); a1 += bf16hi_to_f32(v.x);
    a2 += bf16lo_to_f32(v.y); a3 += bf16hi_to_f32(v.y);
    a4 += bf16lo_to_f32(v.z); a5 += bf16hi_to_f32(v.z);
    a6 += bf16lo_to_f32(v.w); a7 += bf16hi_to_f32(v.w);
  }

  if (row < N) {
    f32x4 r0, r1;
    r0[0] = fmaxf(a0, 0.0f); r0[1] = fmaxf(a1, 0.0f);
    r0[2] = fmaxf(a2, 0.0f); r0[3] = fmaxf(a3, 0.0f);
    r1[0] = fmaxf(a4, 0.0f); r1[1] = fmaxf(a5, 0.0f);
    r1[2] = fmaxf(a6, 0.0f); r1[3] = fmaxf(a7, 0.0f);
    float* op = out + (size_t)row * 256 + c0;
    *(f32x4*)op = r0;
    *(f32x4*)(op + 4) = r1;
  }
}

extern "C" void kernel_launch(void* const* d_in, const int* in_sizes, int n_in,
                              void* d_out, int out_size, void* d_ws, size_t ws_size,
                              hipStream_t stream) {
  const float* x        = (const float*)d_in[0];
  const float* W        = (const float*)d_in[1];
  const float* b        = (const float*)d_in[2];
  const int*   b_from_a = (const int*)d_in[3];
  const int*   a_from_b = (const int*)d_in[4];
  float*       out      = (float*)d_out;
  const int M = in_sizes[0] / 256;  // 50000 atoms

  unsigned short* h = (unsigned short*)d_ws;              // bf16 h, 25.6 MB
  const size_t h_bytes   = (size_t)M * 256 * sizeof(unsigned short);
  const size_t a2a_bytes = (size_t)M * 16 * sizeof(int);  // 3.2 MB

  if (ws_size >= h_bytes + a2a_bytes) {
    int* a2a = (int*)((char*)d_ws + h_bytes);
    const int n = M * 16;
    gin_a2a<<<(n / 4 + 255) / 256, 256, 0, stream>>>(b_from_a, a_from_b, a2a, n);
    gin_gemm<<<(M + 63) / 64, 256, 0, stream>>>(x, W, b, h, M, 1);
    gin_gather_sliced<<<2048, 256, 0, stream>>>(h, a2a, out, M);
  } else {
    gin_gemm<<<(M + 63) / 64, 256, 0, stream>>>(x, W, b, h, M, 0);
    gin_gather<<<(M + 7) / 8, 256, 0, stream>>>(h, b_from_a, a_from_b, out, M);
  }
}